// Round 4
// baseline (423.068 us; speedup 1.0000x reference)
//
#include <hip/hip_runtime.h>
#include <math.h>

#define BB 1024
#define CC 50000
#define DD 256
#define LRATE 0.5f

#define C4 (CC / 4)            // 12,500 uint4 per y row
#define Q4 (BB * C4)           // 12,800,000 uint4 in all of y

// ------------------------------------------------------------------
// K1 (VERBATIM from the proven 421us baseline):
// out_center = center (float4 copy) AND zero the class counts.
__global__ void k_init(const float4* __restrict__ center,
                       float4* __restrict__ out_center,
                       int4* __restrict__ counts) {
    int i = blockIdx.x * blockDim.x + threadIdx.x;
    const int n4 = CC * DD / 4;         // 3,200,000
    if (i < n4) out_center[i] = center[i];
    if (i < CC / 4)                     // 12,500 int4
        counts[i] = make_int4(0, 0, 0, 0);
}

// ------------------------------------------------------------------
// K2 (new, minimal): flat label scan. One uint4 of y per thread,
// 50000 blocks x 256 = 12.8M threads, perfectly coalesced single
// 204.8 MB streaming read. Exactly one thread per row sees nonzero
// bits (the 1.0f) and plain-stores labels[b] — single writer.
__global__ void k_scan(const uint4* __restrict__ y4,
                       int* __restrict__ labels) {
    unsigned q = blockIdx.x * blockDim.x + threadIdx.x;   // < Q4
    uint4 v = y4[q];
    if (v.x | v.y | v.z | v.w) {
        unsigned b = q / (unsigned)C4;                    // magic-mul div
        unsigned j = q - b * (unsigned)C4;
        labels[b] = 4 * j + (v.x ? 0 : (v.y ? 1 : (v.z ? 2 : 3)));
    }
}

// ------------------------------------------------------------------
// K3: per-row update (baseline's k_labels_update minus the chunked
// scan — label now comes from ws). 1024 blocks x 256.
__global__ void k_update(const int* __restrict__ labels,
                         const float* __restrict__ x,
                         const float* __restrict__ center,
                         float* __restrict__ out_center,
                         int* __restrict__ counts,
                         float* __restrict__ loss_norm) {
    int b = blockIdx.x;
    int lab = labels[b];
    lab = (unsigned)lab >= (unsigned)CC ? 0 : lab;        // safety

    int d = threadIdx.x;                                  // DD == blockDim.x
    float dist = x[(size_t)b * DD + d] - center[(size_t)lab * DD + d];
    atomicAdd(&out_center[(size_t)lab * DD + d], LRATE * dist);
    if (d == 0) atomicAdd(&counts[lab], 1);

    float sq = dist * dist;
    #pragma unroll
    for (int off = 32; off > 0; off >>= 1)
        sq += __shfl_down(sq, off, 64);

    __shared__ float s_part[4];
    if ((d & 63) == 0) s_part[d >> 6] = sq;
    __syncthreads();
    if (d == 0)
        loss_norm[b] = sqrtf(s_part[0] + s_part[1] + s_part[2] + s_part[3]);
}

// ------------------------------------------------------------------
// K4 (VERBATIM from the proven 421us baseline):
// loss[b,c] = loss_norm[b] / (counts[c] + 1).
#define ROWS_PER_BLK 16
__global__ void k_loss(const float* __restrict__ loss_norm,
                       const int* __restrict__ counts,
                       float* __restrict__ out_loss) {
    const int c4n = CC / 4;             // 12500
    int c4 = blockIdx.x * blockDim.x + threadIdx.x;
    if (c4 >= c4n) return;
    int4 cnt = ((const int4*)counts)[c4];
    float4 inv;
    inv.x = 1.0f / ((float)cnt.x + 1.0f);
    inv.y = 1.0f / ((float)cnt.y + 1.0f);
    inv.z = 1.0f / ((float)cnt.z + 1.0f);
    inv.w = 1.0f / ((float)cnt.w + 1.0f);
    int b0 = blockIdx.y * ROWS_PER_BLK;
    #pragma unroll
    for (int r = 0; r < ROWS_PER_BLK; ++r) {
        int b = b0 + r;
        float ln = loss_norm[b];
        float4 o;
        o.x = ln * inv.x; o.y = ln * inv.y; o.z = ln * inv.z; o.w = ln * inv.w;
        ((float4*)(out_loss + (size_t)b * CC))[c4] = o;
    }
}

// ------------------------------------------------------------------
extern "C" void kernel_launch(void* const* d_in, const int* in_sizes, int n_in,
                              void* d_out, int out_size, void* d_ws, size_t ws_size,
                              hipStream_t stream) {
    const float* x        = (const float*)d_in[0];          // [B, D]
    const unsigned int* y = (const unsigned int*)d_in[1];   // [B, C] one-hot fp32 bits
    const float* center   = (const float*)d_in[2];          // [C, D]

    float* out_loss   = (float*)d_out;                      // [B, C]
    float* out_center = (float*)d_out + (size_t)BB * CC;    // [C, D]

    // workspace layout IDENTICAL to the proven baseline:
    //   counts    @ 0       (200,000 B)
    //   loss_norm @ 262,144 (4,096 B)   <- baseline's 256KB offset
    //   labels    @ 200,704 (4,096 B)   <- unused gap inside baseline footprint
    int*   counts    = (int*)d_ws;
    float* loss_norm = (float*)((char*)d_ws + 256 * 1024);
    int*   labels    = (int*)((char*)d_ws + 200704);

    k_init<<<CC * DD / 4 / 256, 256, 0, stream>>>(
        (const float4*)center, (float4*)out_center, (int4*)counts);

    k_scan<<<Q4 / 256, 256, 0, stream>>>(
        (const uint4*)y, labels);

    k_update<<<BB, DD, 0, stream>>>(
        labels, x, center, out_center, counts, loss_norm);

    dim3 lgrid((CC / 4 + 255) / 256, BB / ROWS_PER_BLK);
    k_loss<<<lgrid, 256, 0, stream>>>(loss_norm, counts, out_loss);
}